// Round 16
// baseline (63.134 us; speedup 1.0000x reference)
//
#include <hip/hip_runtime.h>

#define T_LEN   131072
#define HID     10
#define CHUNK   16
#define WARM    32
#define CPB     4                      // chains per block (one wave)
#define SPAN    (CPB * CHUNK)          // 64 outputs per block
#define NBLK    (T_LEN / SPAN)         // 2048 -> 2 waves per SIMD
#define SMAX    (WARM + CHUNK + 1)     // 49

typedef float pk2 __attribute__((ext_vector_type(2)));
struct f4v { pk2 lo, hi; };            // 4 chains: lo={c0,c1}, hi={c2,c3}

#if __has_builtin(__builtin_amdgcn_exp2f)
#define EXP2(x) __builtin_amdgcn_exp2f(x)
#else
#define EXP2(x) exp2f(x)
#endif

#if __has_builtin(__builtin_amdgcn_rcpf)
#define RCP(x) __builtin_amdgcn_rcpf(x)
#else
#define RCP(x) (1.0f / (x))
#endif

template <int q>
__device__ __forceinline__ float qbcast(float v) {
#if __has_builtin(__builtin_amdgcn_mov_dpp)
    return __int_as_float(__builtin_amdgcn_mov_dpp(__float_as_int(v), q * 0x55, 0xF, 0xF, true));
#else
    return __shfl(v, (threadIdx.x & ~3) + q, 64);
#endif
}

__device__ __forceinline__ pk2 pfma(pk2 a, pk2 b, pk2 c) {
#if __has_builtin(__builtin_elementwise_fma)
    return __builtin_elementwise_fma(a, b, c);
#else
    pk2 r; r.x = fmaf(a.x, b.x, c.x); r.y = fmaf(a.y, b.y, c.y); return r;
#endif
}

__device__ __forceinline__ f4v ffma(pk2 w, const f4v& a, const f4v& c) {
    return f4v{ pfma(w, a.lo, c.lo), pfma(w, a.hi, c.hi) };
}
__device__ __forceinline__ f4v fmul2(pk2 w, const f4v& a) {
    return f4v{ w * a.lo, w * a.hi };
}
__device__ __forceinline__ f4v fadd(const f4v& a, const f4v& b) {
    return f4v{ a.lo + b.lo, a.hi + b.hi };
}

__global__ __launch_bounds__(64, 2)
void lstm_chunk_kernel(const float* __restrict__ x,
                       const float* __restrict__ h_out,
                       const float* __restrict__ Wih0, const float* __restrict__ Whh0,
                       const float* __restrict__ bih0, const float* __restrict__ bhh0,
                       const float* __restrict__ Wih1, const float* __restrict__ Whh1,
                       const float* __restrict__ bih1, const float* __restrict__ bhh1,
                       const float* __restrict__ fc_w, const float* __restrict__ fc_b,
                       float* __restrict__ out)
{
    const int lane = threadIdx.x;           // 0..63
    const int j = lane >> 2;                // hidden unit
    const int p = lane & 3;                 // gate: 0=i 1=f 2=g 3=o
    const bool act = (j < HID);
    const int r = act ? (p * HID + j) : 0;

    // ---- per-lane weights as pk2 {w,w}: one register pair serves both f4v
    //      halves (all 4 chains share weights) ----
    pk2 wh0d[HID], wh1d[HID], wi1d[HID], wi0d[4];
#pragma unroll
    for (int k = 0; k < HID; ++k) {
        const float a0 = act ? Whh0[r * HID + k] : 0.f;
        const float a1 = act ? Whh1[r * HID + k] : 0.f;
        const float a2 = act ? Wih1[r * HID + k] : 0.f;
        wh0d[k] = pk2{a0, a0};
        wh1d[k] = pk2{a1, a1};
        wi1d[k] = pk2{a2, a2};
    }
#pragma unroll
    for (int k = 0; k < 4; ++k) {
        const float w = act ? Wih0[r * 4 + k] : 0.f;
        wi0d[k] = pk2{w, w};
    }
    const float b0s = act ? (bih0[r] + bhh0[r]) : 0.f;
    float b1s = act ? (bih1[r] + bhh1[r]) : 0.f;

    // fc piggyback: lane 40's L1 "gate row" = fc_w, bias fc_b; its L1
    // pre-activation each iter = fc(h1 two steps back), all 4 chains.
    if (j == HID && p == 0) {
#pragma unroll
        for (int k = 0; k < HID; ++k) { const float w = fc_w[k]; wh1d[k] = pk2{w, w}; }
        b1s = fc_b[0];
    }
    const pk2 b0p = pk2{b0s, b0s};
    const pk2 b1p = pk2{b1s, b1s};
    const f4v b0f = f4v{b0p, b0p};
    const f4v b1f = f4v{b1p, b1p};

    const float KLN = 1.4426950408889634f;
    const bool isg = (p == 2);
    const float m1 = isg ? (-2.f * KLN) : (-KLN);
    const float Av = isg ? 2.f : 1.f;
    const float Bv = isg ? -1.f : 0.f;
    const pk2 m1p  = pk2{m1, m1};
    const pk2 avp  = pk2{Av, Av};
    const pk2 bvp  = pk2{Bv, Bv};
    const pk2 onep = pk2{1.f, 1.f};
    const pk2 twop = pk2{2.f, 2.f};
    const pk2 negp = pk2{-1.f, -1.f};
    const pk2 k2p  = pk2{-2.f * KLN, -2.f * KLN};

    // ---- geometry: chain q covers t0[q] = b*SPAN + q*CHUNK .. +CHUNK-1 ----
    const int b = blockIdx.x;
    const int t00 = b * SPAN;
    const int t0q1 = t00 + CHUNK, t0q2 = t00 + 2 * CHUNK, t0q3 = t00 + 3 * CHUNK;
    const int tb0 = (t00  > WARM) ? (t00  - WARM) : 0;
    const int tb1 = (t0q1 > WARM) ? (t0q1 - WARM) : 0;
    const int tb2 = (t0q2 > WARM) ? (t0q2 - WARM) : 0;
    const int tb3 = (t0q3 > WARM) ? (t0q3 - WARM) : 0;
    const int sb0 = (t00  - tb0) + 2;
    const int sb1 = (t0q1 - tb1) + 2;
    const int sb2 = (t0q2 - tb2) + 2;
    const int sb3 = (t0q3 - tb3) + 2;

    // ---- states (f4v components = chains). h_out carry loaded for chains
    //      whose warm window reaches t=0 (b==0). ----
    f4v hp0 = f4v{pk2{0.f,0.f}, pk2{0.f,0.f}};
    f4v hp1 = hp0, cp0 = hp0, cp1 = hp0;
    if (b == 0) {
        const float c0 = act ? h_out[j] : 0.f;
        const float c1 = act ? h_out[HID + j] : 0.f;
        // chains 0,1,2 have tbeg==0 (q*16 <= 32); chain 3 warm-starts at t=16
        hp0.lo = pk2{c0, c0}; hp0.hi.x = c0;
        hp1.lo = pk2{c1, c1}; hp1.hi.x = c1;
    }

    // ---- LDS: ONLY h-broadcast buffer + output buffer (x via global) ----
    __shared__ float4 hbuf4[2 * HID];
    __shared__ float  outbuf[SPAN];
    const float4* xg = (const float4*)x;

    // ---- x loads: direct global, clamped (tail reads are discarded) ----
    auto ld0 = [&](int s) -> float4 { int g = tb0 + s; g = (g < T_LEN) ? g : (T_LEN - 1); return xg[g]; };
    auto ld1 = [&](int s) -> float4 { int g = tb1 + s; g = (g < T_LEN) ? g : (T_LEN - 1); return xg[g]; };
    auto ld2 = [&](int s) -> float4 { int g = tb2 + s; g = (g < T_LEN) ? g : (T_LEN - 1); return xg[g]; };
    auto ld3 = [&](int s) -> float4 { int g = tb3 + s; g = (g < T_LEN) ? g : (T_LEN - 1); return xg[g]; };

    // transpose 4 per-chain float4 -> component-major f4v[4]
    auto xpose = [&](const float4& a, const float4& c, const float4& d, const float4& e,
                     f4v (&xk)[4]) {
        xk[0] = f4v{pk2{a.x, c.x}, pk2{d.x, e.x}};
        xk[1] = f4v{pk2{a.y, c.y}, pk2{d.y, e.y}};
        xk[2] = f4v{pk2{a.z, c.z}, pk2{d.z, e.z}};
        xk[3] = f4v{pk2{a.w, c.w}, pk2{d.w, e.w}};
    };

    // ---- h broadcast via LDS float4 (verified 1.2207e-4 path, R13/R14):
    //      2 masked ds_write_b128 + 20 b128 broadcast reads ----
    f4v sh0[HID], sh1[HID];
    auto publish = [&]() {
        if (p == 0 && act) {
            hbuf4[2 * j]     = make_float4(hp0.lo.x, hp0.lo.y, hp0.hi.x, hp0.hi.y);
            hbuf4[2 * j + 1] = make_float4(hp1.lo.x, hp1.lo.y, hp1.hi.x, hp1.hi.y);
        }
    };
    auto fetch = [&]() {
#pragma unroll
        for (int k = 0; k < HID; ++k) {
            const float4 a = hbuf4[2 * k];
            const float4 c = hbuf4[2 * k + 1];
            sh0[k] = f4v{pk2{a.x, a.y}, pk2{a.z, a.w}};
            sh1[k] = f4v{pk2{c.x, c.y}, pk2{c.z, c.w}};
        }
    };

    auto nonlin = [&](const f4v& ap, f4v& cpL, f4v& hpL) {
        pk2 tl = m1p * ap.lo, th = m1p * ap.hi;
        tl.x = EXP2(tl.x); tl.y = EXP2(tl.y);
        th.x = EXP2(th.x); th.y = EXP2(th.y);
        pk2 ul = tl + onep, uh = th + onep;
        ul.x = RCP(ul.x); ul.y = RCP(ul.y);
        uh.x = RCP(uh.x); uh.y = RCP(uh.y);
        const pk2 yl = pfma(avp, ul, bvp), yh = pfma(avp, uh, bvp);
        const pk2 gil = pk2{qbcast<0>(yl.x), qbcast<0>(yl.y)}, gih = pk2{qbcast<0>(yh.x), qbcast<0>(yh.y)};
        const pk2 gfl = pk2{qbcast<1>(yl.x), qbcast<1>(yl.y)}, gfh = pk2{qbcast<1>(yh.x), qbcast<1>(yh.y)};
        const pk2 ggl = pk2{qbcast<2>(yl.x), qbcast<2>(yl.y)}, ggh = pk2{qbcast<2>(yh.x), qbcast<2>(yh.y)};
        const pk2 gol = pk2{qbcast<3>(yl.x), qbcast<3>(yl.y)}, goh = pk2{qbcast<3>(yh.x), qbcast<3>(yh.y)};
        cpL.lo = pfma(gfl, cpL.lo, gil * ggl);
        cpL.hi = pfma(gfh, cpL.hi, gih * ggh);
        pk2 ttl = k2p * cpL.lo, tth = k2p * cpL.hi;
        ttl.x = EXP2(ttl.x); ttl.y = EXP2(ttl.y);
        tth.x = EXP2(tth.x); tth.y = EXP2(tth.y);
        pk2 vl = ttl + onep, vh = tth + onep;
        vl.x = RCP(vl.x); vl.y = RCP(vl.y);
        vh.x = RCP(vh.x); vh.y = RCP(vh.y);
        hpL.lo = gol * pfma(twop, vl, negp);
        hpL.hi = goh * pfma(twop, vh, negp);
    };

    auto l0dot = [&](const f4v (&xk)[4]) -> f4v {
        f4v aA = ffma(wh0d[0], sh0[0], b0f);
        aA = ffma(wh0d[3], sh0[3], aA);
        aA = ffma(wh0d[6], sh0[6], aA);
        aA = ffma(wh0d[9], sh0[9], aA);
        f4v aB = fmul2(wi0d[0], xk[0]);
        aB = ffma(wi0d[1], xk[1], aB);
        aB = ffma(wh0d[1], sh0[1], aB);
        aB = ffma(wh0d[4], sh0[4], aB);
        aB = ffma(wh0d[7], sh0[7], aB);
        f4v aC = fmul2(wi0d[2], xk[2]);
        aC = ffma(wi0d[3], xk[3], aC);
        aC = ffma(wh0d[2], sh0[2], aC);
        aC = ffma(wh0d[5], sh0[5], aC);
        aC = ffma(wh0d[8], sh0[8], aC);
        return fadd(fadd(aA, aB), aC);
    };

    // fused step: L0 @ t, L1 @ t-1 (reads OLD sh). Returns L1 pre-activation.
    auto fstep = [&](const f4v (&xk)[4]) -> f4v {
        const f4v ap0 = l0dot(xk);
        f4v dA = ffma(wi1d[0], sh0[0], b1f);
        dA = ffma(wi1d[4], sh0[4], dA);
        dA = ffma(wi1d[8], sh0[8], dA);
        dA = ffma(wh1d[2], sh1[2], dA);
        dA = ffma(wh1d[6], sh1[6], dA);
        f4v dB = fmul2(wi1d[1], sh0[1]);
        dB = ffma(wi1d[5], sh0[5], dB);
        dB = ffma(wi1d[9], sh0[9], dB);
        dB = ffma(wh1d[3], sh1[3], dB);
        dB = ffma(wh1d[7], sh1[7], dB);
        f4v dC = fmul2(wi1d[2], sh0[2]);
        dC = ffma(wi1d[6], sh0[6], dC);
        dC = ffma(wh1d[0], sh1[0], dC);
        dC = ffma(wh1d[4], sh1[4], dC);
        dC = ffma(wh1d[8], sh1[8], dC);
        f4v dD = fmul2(wi1d[3], sh0[3]);
        dD = ffma(wi1d[7], sh0[7], dD);
        dD = ffma(wh1d[1], sh1[1], dD);
        dD = ffma(wh1d[5], sh1[5], dD);
        dD = ffma(wh1d[9], sh1[9], dD);
        const f4v ap1 = fadd(fadd(dA, dB), fadd(dC, dD));
        nonlin(ap0, cp0, hp0);
        nonlin(ap1, cp1, hp1);
        return ap1;
    };

    // ---- prologue: initial publish/fetch, L0-only peel @ slot 0 ----
    publish(); fetch();
    {
        f4v x0[4];
        xpose(ld0(0), ld1(0), ld2(0), ld3(0), x0);
        nonlin(l0dot(x0), cp0, hp0);
    }
    publish(); fetch();

    // ---- 2-deep raw-register x pipeline (vmcnt only; no LDS) ----
    float4 rc0 = ld0(1), rc1 = ld1(1), rc2 = ld2(1), rc3 = ld3(1);
    float4 rn0 = ld0(2), rn1 = ld1(2), rn2 = ld2(2), rn3 = ld3(2);

    float hf0 = 0.f, hf1 = 0.f;

    // ---- main loop: iter s = L0@tbeg+s, L1@tbeg+s-1 (per-chain time) ----
    for (int s = 1; s <= SMAX; ++s) {
        f4v xk[4];
        xpose(rc0, rc1, rc2, rc3, xk);
        rc0 = rn0; rc1 = rn1; rc2 = rn2; rc3 = rn3;
        rn0 = ld0(s + 2); rn1 = ld1(s + 2); rn2 = ld2(s + 2); rn3 = ld3(s + 2);
        const f4v ap1 = fstep(xk);
        publish();
        fetch();
        if (s == WARM + CHUNK - 1) hf0 = hp0.hi.y;   // chain 3 h0 @ its t1
        if (s == WARM + CHUNK)     hf1 = hp1.hi.y;   // chain 3 h1 @ its t1
        if (lane == 4 * HID) {
            const unsigned i0 = (unsigned)(s - sb0); if (i0 < CHUNK) outbuf[i0] = ap1.lo.x;
            const unsigned i1 = (unsigned)(s - sb1); if (i1 < CHUNK) outbuf[CHUNK + i1] = ap1.lo.y;
            const unsigned i2 = (unsigned)(s - sb2); if (i2 < CHUNK) outbuf[2 * CHUNK + i2] = ap1.hi.x;
            const unsigned i3 = (unsigned)(s - sb3); if (i3 < CHUNK) outbuf[3 * CHUNK + i3] = ap1.hi.y;
        }
    }

    // ---- coalesced store: 4 chunks = 64 outputs ----
    out[t00 + lane] = outbuf[lane];

    // ---- h_final from chain 3 of the last block ----
    if (b == NBLK - 1 && p == 0 && act) {
        out[T_LEN + j] = hf0;
        out[T_LEN + HID + j] = hf1;
    }
}

extern "C" void kernel_launch(void* const* d_in, const int* in_sizes, int n_in,
                              void* d_out, int out_size, void* d_ws, size_t ws_size,
                              hipStream_t stream) {
    const float* x    = (const float*)d_in[0];
    const float* hout = (const float*)d_in[1];
    const float* Wih0 = (const float*)d_in[2];
    const float* Whh0 = (const float*)d_in[3];
    const float* bih0 = (const float*)d_in[4];
    const float* bhh0 = (const float*)d_in[5];
    const float* Wih1 = (const float*)d_in[6];
    const float* Whh1 = (const float*)d_in[7];
    const float* bih1 = (const float*)d_in[8];
    const float* bhh1 = (const float*)d_in[9];
    const float* fcw  = (const float*)d_in[10];
    const float* fcb  = (const float*)d_in[11];
    float* out = (float*)d_out;

    hipLaunchKernelGGL(lstm_chunk_kernel, dim3(NBLK), dim3(64), 0, stream,
                       x, hout, Wih0, Whh0, bih0, bhh0,
                       Wih1, Whh1, bih1, bhh1, fcw, fcb, out);
}

// Round 17
// 38.034 us; speedup vs baseline: 1.6600x; 1.6600x over previous
//
#include <hip/hip_runtime.h>

#define T_LEN   131072
#define HID     10
#define CHUNK   32
#define WARM    32
#define CPB     4                       // chains per block (one wave)
#define SPAN    (CPB * CHUNK)           // 128 outputs per block
#define NBLK    (T_LEN / SPAN)          // 1024
#define SMAX    (WARM + CHUNK + 1)      // 65
#define HSTR    17                      // hbuf stride: spreads banks across chains

#if __has_builtin(__builtin_amdgcn_exp2f)
#define EXP2(x) __builtin_amdgcn_exp2f(x)
#else
#define EXP2(x) exp2f(x)
#endif

#if __has_builtin(__builtin_amdgcn_rcpf)
#define RCP(x) __builtin_amdgcn_rcpf(x)
#else
#define RCP(x) (1.0f / (x))
#endif

__global__ __launch_bounds__(64, 1)
void lstm_chunk_kernel(const float* __restrict__ x,
                       const float* __restrict__ h_out,
                       const float* __restrict__ Wih0, const float* __restrict__ Whh0,
                       const float* __restrict__ bih0, const float* __restrict__ bhh0,
                       const float* __restrict__ Wih1, const float* __restrict__ Whh1,
                       const float* __restrict__ bih1, const float* __restrict__ bhh1,
                       const float* __restrict__ fc_w, const float* __restrict__ fc_b,
                       float* __restrict__ out)
{
    const int lane = threadIdx.x;       // 0..63
    const int c = lane >> 4;            // chain 0..3
    const int j = lane & 15;            // unit 0..15 (j<10 active, j==10 = fc lane)
    const bool uact = (j < HID);
    const bool isfc = (j == HID);
    const int jj = uact ? j : 0;        // safe row index for weight loads

    // ---- per-lane weights: this lane owns ALL FOUR gate rows of unit j ----
    // rows r_p = p*HID + j (PyTorch gate order i,f,g,o)
    float wi0[4][4], wh0[4][HID], b0v[4];
    float wi1[4][HID], wh1[4][HID], b1v[4];
#pragma unroll
    for (int p = 0; p < 4; ++p) {
        const int r = p * HID + jj;
        b0v[p] = uact ? (bih0[r] + bhh0[r]) : 0.f;
        b1v[p] = uact ? (bih1[r] + bhh1[r]) : 0.f;
#pragma unroll
        for (int m = 0; m < 4; ++m) wi0[p][m] = uact ? Wih0[r * 4 + m] : 0.f;
#pragma unroll
        for (int k = 0; k < HID; ++k) {
            wh0[p][k] = uact ? Whh0[r * HID + k] : 0.f;
            wi1[p][k] = uact ? Wih1[r * HID + k] : 0.f;
            wh1[p][k] = uact ? Whh1[r * HID + k] : 0.f;
        }
    }
    // fc piggyback: the j==10 lane's L1 row 0 is the fc layer; its d[0]
    // pre-activation each iteration = fc(h1 two steps back) + fc_b.
    if (isfc) {
#pragma unroll
        for (int k = 0; k < HID; ++k) wh1[0][k] = fc_w[k];
        b1v[0] = fc_b[0];
    }

    const float KLN = 1.4426950408889634f;   // log2(e)

    // ---- geometry: chain c covers t0q = b*SPAN + c*CHUNK .. +CHUNK-1 ----
    const int b = blockIdx.x;
    const int t00 = b * SPAN;
    const int t0q = t00 + c * CHUNK;
    const int tb  = (t0q > WARM) ? (t0q - WARM) : 0;  // clamped warm start
    const int sb  = (t0q - tb) + 2;                   // emit-window start

    // ---- state (scalar per lane: unit j of chain c) ----
    float h0 = (tb == 0 && uact) ? h_out[j] : 0.f;
    float h1 = (tb == 0 && uact) ? h_out[HID + j] : 0.f;
    float c0 = 0.f, c1 = 0.f;

    // ---- LDS: h broadcast (stride-17 banks => <=2-way aliasing, free) ----
    __shared__ float hbuf0[CPB * HSTR];
    __shared__ float hbuf1[CPB * HSTR];
    __shared__ float outbuf[SPAN];
    const float4* xg = (const float4*)x;

    auto publish = [&]() {   // all 64 lanes write; slots j>=10 never read
        hbuf0[c * HSTR + j] = h0;
        hbuf1[c * HSTR + j] = h1;
    };
    float sh0[HID], sh1[HID];
    auto fetch = [&]() {
#pragma unroll
        for (int k = 0; k < HID; ++k) {
            sh0[k] = hbuf0[c * HSTR + k];
            sh1[k] = hbuf1[c * HSTR + k];
        }
    };

    auto sigm = [&](float a) { return RCP(1.f + EXP2(-KLN * a)); };
    auto tanh_ = [&](float a) { return fmaf(2.f, RCP(1.f + EXP2(-2.f * KLN * a)), -1.f); };

    // L0 @ t: 4 gate-row dots (2 accumulators each), fully in-lane update
    auto stepL0 = [&](const float4& xv) {
        float a[4];
#pragma unroll
        for (int p = 0; p < 4; ++p) {
            float u = b0v[p], v = 0.f;
            u = fmaf(wi0[p][0], xv.x, u); v = fmaf(wi0[p][1], xv.y, v);
            u = fmaf(wi0[p][2], xv.z, u); v = fmaf(wi0[p][3], xv.w, v);
#pragma unroll
            for (int k = 0; k < HID; k += 2) {
                u = fmaf(wh0[p][k],     sh0[k],     u);
                v = fmaf(wh0[p][k + 1], sh0[k + 1], v);
            }
            a[p] = u + v;
        }
        const float gi = sigm(a[0]), gf = sigm(a[1]);
        const float gg = tanh_(a[2]), go = sigm(a[3]);
        c0 = fmaf(gf, c0, gi * gg);
        h0 = go * tanh_(c0);
    };

    // L1 @ t-1 (uses OLD sh0 as input, OLD sh1 recurrent). Returns d[0]
    // (fc lane: the fc pre-activation).
    auto stepL1 = [&]() -> float {
        float d[4];
#pragma unroll
        for (int p = 0; p < 4; ++p) {
            float u = b1v[p], v = 0.f;
#pragma unroll
            for (int k = 0; k < HID; k += 2) {
                u = fmaf(wi1[p][k],     sh0[k],     u);
                v = fmaf(wi1[p][k + 1], sh0[k + 1], v);
            }
#pragma unroll
            for (int k = 0; k < HID; k += 2) {
                u = fmaf(wh1[p][k],     sh1[k],     u);
                v = fmaf(wh1[p][k + 1], sh1[k + 1], v);
            }
            d[p] = u + v;
        }
        const float gi = sigm(d[0]), gf = sigm(d[1]);
        const float gg = tanh_(d[2]), go = sigm(d[3]);
        c1 = fmaf(gf, c1, gi * gg);
        h1 = go * tanh_(c1);
        return d[0];
    };

    // x load for this lane's chain (clamped; clamped reads are discarded)
    auto ldx = [&](int s) -> float4 {
        int g = tb + s; g = (g < T_LEN) ? g : (T_LEN - 1);
        return xg[g];
    };

    // ---- prologue: publish initial state; L0-only peel @ slot 0 ----
    publish(); fetch();
    stepL0(ldx(0));
    publish(); fetch();

    float4 xc = ldx(1), xn = ldx(2);    // 2-deep register prefetch (vmcnt)

    float hf0 = 0.f, hf1 = 0.f;

    // ---- main loop: iter s = L0@tb+s, L1@tb+s-1 (per-chain time) ----
    for (int s = 1; s <= SMAX; ++s) {
        const float4 xv = xc;
        xc = xn;
        xn = ldx(s + 2);
        stepL0(xv);                     // uses OLD sh0
        const float d0 = stepL1();      // uses OLD sh0, OLD sh1
        publish();
        fetch();
        if (s == WARM + CHUNK - 1) hf0 = h0;   // chain 3 lanes: h0 @ its t1
        if (s == WARM + CHUNK)     hf1 = h1;   // chain 3 lanes: h1 @ its t1
        if (isfc) {
            const unsigned i_ = (unsigned)(s - sb);
            if (i_ < (unsigned)CHUNK) outbuf[c * CHUNK + i_] = d0;
        }
    }

    // ---- coalesced store: 4 chunks = 128 outputs ----
    out[t00 + lane] = outbuf[lane];
    out[t00 + 64 + lane] = outbuf[64 + lane];

    // ---- h_final from chain 3 of the last block ----
    if (b == NBLK - 1 && c == 3 && uact) {
        out[T_LEN + j] = hf0;
        out[T_LEN + HID + j] = hf1;
    }
}

extern "C" void kernel_launch(void* const* d_in, const int* in_sizes, int n_in,
                              void* d_out, int out_size, void* d_ws, size_t ws_size,
                              hipStream_t stream) {
    const float* x    = (const float*)d_in[0];
    const float* hout = (const float*)d_in[1];
    const float* Wih0 = (const float*)d_in[2];
    const float* Whh0 = (const float*)d_in[3];
    const float* bih0 = (const float*)d_in[4];
    const float* bhh0 = (const float*)d_in[5];
    const float* Wih1 = (const float*)d_in[6];
    const float* Whh1 = (const float*)d_in[7];
    const float* bih1 = (const float*)d_in[8];
    const float* bhh1 = (const float*)d_in[9];
    const float* fcw  = (const float*)d_in[10];
    const float* fcb  = (const float*)d_in[11];
    float* out = (float*)d_out;

    hipLaunchKernelGGL(lstm_chunk_kernel, dim3(NBLK), dim3(64), 0, stream,
                       x, hout, Wih0, Whh0, bih0, bhh0,
                       Wih1, Whh1, bih1, bhh1, fcw, fcb, out);
}